// Round 1
// baseline (414.367 us; speedup 1.0000x reference)
//
#include <hip/hip_runtime.h>
#include <hip/hip_bf16.h>

// Problem constants: b=4, n=8192, dim=256, heads=8, dhead=64, inner=512
#define SEQ    8192
#define NROWS  32768      // b*n
#define F3     1536       // 3*inner
#define EPS    1e-5f

typedef __attribute__((ext_vector_type(4))) float f32x4;
typedef __attribute__((ext_vector_type(8))) short bf16x8;   // 8 bf16 in 4 VGPRs (MFMA A/B frag)

__device__ __forceinline__ unsigned short f2bu(float f) {
  __hip_bfloat16 h = __float2bfloat16(f);
  return __builtin_bit_cast(unsigned short, h);
}
__device__ __forceinline__ float b2f(unsigned short u) {
  return __bfloat162float(__builtin_bit_cast(__hip_bfloat16, u));
}

// ---------------------------------------------------------------- convert f32 -> bf16 (x4 vectorized)
__global__ __launch_bounds__(256) void convert_kernel(const float* __restrict__ in,
                                                      unsigned short* __restrict__ out, int n4) {
  int i = blockIdx.x * 256 + threadIdx.x;
  if (i >= n4) return;
  float4 v = reinterpret_cast<const float4*>(in)[i];
  ushort4 o;
  o.x = f2bu(v.x); o.y = f2bu(v.y); o.z = f2bu(v.z); o.w = f2bu(v.w);
  reinterpret_cast<ushort4*>(out)[i] = o;
}

// ---------------------------------------------------------------- bf16 MFMA GEMM: C[m,c] = sum_k A[m,k]*Bw[c,k]
// m97 structure: 128x128 tile, BK=64, 4 waves (2x2 of 64x64), global_load_lds width=16, 2-barrier loop.
// PERB: weights indexed per-batch (b = row/8192), for the q @ M2^T tail GEMM.
template<int K, int LDA, int LDC, bool PERB, bool BIAS, bool OUTF32>
__global__ __launch_bounds__(256) void gemm_kernel(const unsigned short* __restrict__ A,
                                                   const unsigned short* __restrict__ Bw,
                                                   const float* __restrict__ bias,
                                                   void* __restrict__ Cout) {
  __shared__ unsigned short As[128 * 64];
  __shared__ unsigned short Bs[128 * 64];
  const int row0 = blockIdx.x * 128;
  const int col0 = blockIdx.y * 128;
  const unsigned short* Bp = Bw;
  if constexpr (PERB) Bp += (size_t)(row0 >> 13) * (size_t)(LDC * K);  // 8192 rows per b, weight [LDC][K]
  const int tid  = threadIdx.x;
  const int lane = tid & 63;
  const int wave = tid >> 6;
  const int wr = (wave >> 1) << 6;       // wave row offset in tile
  const int wc = (wave & 1) << 6;        // wave col offset in tile
  const int srow = tid >> 3;             // staging: row within 32-row pass
  const int scol = (tid & 7) << 3;       // staging: elem col (8 bf16 = 16B)

  f32x4 acc[4][4] = {};

  for (int k0 = 0; k0 < K; k0 += 64) {
#pragma unroll
    for (int it = 0; it < 4; ++it) {
      const unsigned short* ga = A + (size_t)(row0 + it * 32 + srow) * LDA + (k0 + scol);
      __builtin_amdgcn_global_load_lds(
          (const __attribute__((address_space(1))) void*)ga,
          (__attribute__((address_space(3))) void*)((char*)As + (it * 4096 + wave * 1024)),
          16, 0, 0);
      const unsigned short* gb = Bp + (size_t)(col0 + it * 32 + srow) * K + (k0 + scol);
      __builtin_amdgcn_global_load_lds(
          (const __attribute__((address_space(1))) void*)gb,
          (__attribute__((address_space(3))) void*)((char*)Bs + (it * 4096 + wave * 1024)),
          16, 0, 0);
    }
    __syncthreads();   // compiler drains vmcnt before s_barrier -> staging complete
#pragma unroll
    for (int ks = 0; ks < 2; ++ks) {
      bf16x8 af[4], bfr[4];
#pragma unroll
      for (int mt = 0; mt < 4; ++mt)
        af[mt] = *reinterpret_cast<const bf16x8*>(
            &As[(wr + mt * 16 + (lane & 15)) * 64 + ks * 32 + (lane >> 4) * 8]);
#pragma unroll
      for (int nt = 0; nt < 4; ++nt)
        bfr[nt] = *reinterpret_cast<const bf16x8*>(
            &Bs[(wc + nt * 16 + (lane & 15)) * 64 + ks * 32 + (lane >> 4) * 8]);
#pragma unroll
      for (int mt = 0; mt < 4; ++mt)
#pragma unroll
        for (int nt = 0; nt < 4; ++nt)
          acc[mt][nt] = __builtin_amdgcn_mfma_f32_16x16x32_bf16(af[mt], bfr[nt], acc[mt][nt], 0, 0, 0);
    }
    __syncthreads();
  }
  // epilogue: C/D layout col=lane&15, row=(lane>>4)*4+i (m89-verified)
#pragma unroll
  for (int mt = 0; mt < 4; ++mt) {
#pragma unroll
    for (int nt = 0; nt < 4; ++nt) {
      const int col = col0 + wc + nt * 16 + (lane & 15);
      float bv = 0.0f;
      if constexpr (BIAS) bv = bias[col];
#pragma unroll
      for (int i = 0; i < 4; ++i) {
        const int row = row0 + wr + mt * 16 + ((lane >> 4) << 2) + i;
        float v = acc[mt][nt][i] + bv;
        if constexpr (OUTF32)
          reinterpret_cast<float*>(Cout)[(size_t)row * LDC + col] = v;
        else
          reinterpret_cast<unsigned short*>(Cout)[(size_t)row * LDC + col] = f2bu(v);
      }
    }
  }
}

// ---------------------------------------------------------------- instance norm over d=64 for k,v regions (in place)
// block = one (b,n) row; 256 threads x 4 elems cover f in [512,1536); 16-lane groups = one head
__global__ __launch_bounds__(256) void norm_kernel(unsigned short* __restrict__ qkv) {
  const int row = blockIdx.x;
  const int t = threadIdx.x;
  unsigned short* p = qkv + (size_t)row * F3 + 512 + t * 4;
  ushort4 raw = *reinterpret_cast<ushort4*>(p);
  float x0 = b2f(raw.x), x1 = b2f(raw.y), x2 = b2f(raw.z), x3 = b2f(raw.w);
  float s  = x0 + x1 + x2 + x3;
  float s2 = x0 * x0 + x1 * x1 + x2 * x2 + x3 * x3;
#pragma unroll
  for (int m = 1; m <= 8; m <<= 1) {
    s  += __shfl_xor(s, m, 64);
    s2 += __shfl_xor(s2, m, 64);
  }
  const float mean = s * (1.0f / 64.0f);
  float var = s2 * (1.0f / 64.0f) - mean * mean;
  var = var < 0.0f ? 0.0f : var;
  const float r = rsqrtf(var + EPS);
  ushort4 o;
  o.x = f2bu((x0 - mean) * r);
  o.y = f2bu((x1 - mean) * r);
  o.z = f2bu((x2 - mean) * r);
  o.w = f2bu((x3 - mean) * r);
  *reinterpret_cast<ushort4*>(p) = o;
}

// ---------------------------------------------------------------- dots[b,h,d,e] = sum_n khat[b,n,h,d]*vhat[b,n,h,e]
// grid (32 bh, 32 n-chunks), block 256. LDS-staged rows, thread owns (d, 16 e's), fp32 atomics.
__global__ __launch_bounds__(256) void dots_kernel(const unsigned short* __restrict__ qkv,
                                                   float* __restrict__ dots) {
  const int bh = blockIdx.x;
  const int chunk = blockIdx.y;
  const int b = bh >> 3, h = bh & 7;
  const int t = threadIdx.x;
  __shared__ float lk[8][64];
  __shared__ float lv[8][64];
  const int d = t & 63;
  const int eg = t >> 6;                  // wave id == e-group (broadcast LDS reads within wave)
  const int lr = t >> 5;                  // staging row 0..7
  const int lc = (t & 31) << 2;           // staging elem 0..124 within 128 (k|v)
  const size_t base = ((size_t)b * SEQ + (size_t)chunk * 256) * F3;
  const int off = (lc < 64) ? (512 + h * 64 + lc) : (1024 + h * 64 + (lc - 64));
  f32x4 acc[4] = {};
  for (int r0 = 0; r0 < 256; r0 += 8) {
    const unsigned short* src = qkv + base + (size_t)(r0 + lr) * F3 + off;
    ushort4 raw = *reinterpret_cast<const ushort4*>(src);
    __syncthreads();                      // previous iteration's reads done
    float4 f;
    f.x = b2f(raw.x); f.y = b2f(raw.y); f.z = b2f(raw.z); f.w = b2f(raw.w);
    float* dst = (lc < 64) ? &lk[lr][lc] : &lv[lr][lc - 64];
    *reinterpret_cast<float4*>(dst) = f;
    __syncthreads();
#pragma unroll
    for (int r = 0; r < 8; ++r) {
      const float kv = lk[r][d];
      const f32x4* vv = reinterpret_cast<const f32x4*>(&lv[r][eg << 4]);
#pragma unroll
      for (int j = 0; j < 4; ++j) acc[j] += kv * vv[j];
    }
  }
  float* dp = dots + (size_t)bh * 4096 + (size_t)d * 64 + (eg << 4);
#pragma unroll
  for (int j = 0; j < 4; ++j) {
    atomicAdd(dp + (j << 2) + 0, acc[j][0]);
    atomicAdd(dp + (j << 2) + 1, acc[j][1]);
    atomicAdd(dp + (j << 2) + 2, acc[j][2]);
    atomicAdd(dp + (j << 2) + 3, acc[j][3]);
  }
}

// ---------------------------------------------------------------- M2[b,c,h*64+d] = (1/n) sum_e dots[b,h,d,e]*Wout[c,h*64+e]
__global__ __launch_bounds__(512) void m2_kernel(const float* __restrict__ dots,
                                                 const float* __restrict__ Wout,
                                                 unsigned short* __restrict__ M2) {
  const int b = blockIdx.x;
  const int c = blockIdx.y;
  const int t = threadIdx.x;              // f' = h*64+d
  __shared__ float wrow[512];
  wrow[t] = Wout[(size_t)c * 512 + t];
  __syncthreads();
  const int h = t >> 6, d = t & 63;
  const float* dp = dots + (size_t)(b * 8 + h) * 4096 + (size_t)d * 64;
  float s = 0.0f;
#pragma unroll 8
  for (int e = 0; e < 64; ++e) s += dp[e] * wrow[(h << 6) + e];
  M2[((size_t)b * 256 + c) * 512 + t] = f2bu(s * (1.0f / 8192.0f));
}

// ---------------------------------------------------------------- launch
extern "C" void kernel_launch(void* const* d_in, const int* in_sizes, int n_in,
                              void* d_out, int out_size, void* d_ws, size_t ws_size,
                              hipStream_t stream) {
  const float* x    = (const float*)d_in[0];   // [4,8192,256]
  const float* Wqkv = (const float*)d_in[1];   // [1536,256]
  const float* Wout = (const float*)d_in[2];   // [256,512]
  const float* bout = (const float*)d_in[3];   // [256]
  char* ws = (char*)d_ws;
  // workspace layout (16B aligned): total ~114.3 MB
  unsigned short* xb    = (unsigned short*)(ws);                 // 16,777,216 B
  unsigned short* wqkvb = (unsigned short*)(ws + 16777216);      //    786,432 B
  unsigned short* qkvb  = (unsigned short*)(ws + 17563648);      // 100,663,296 B
  float*          dots  = (float*)         (ws + 118226944);     //    524,288 B
  unsigned short* m2    = (unsigned short*)(ws + 118751232);     //  1,048,576 B

  hipMemsetAsync(dots, 0, 524288, stream);
  convert_kernel<<<dim3(8192), 256, 0, stream>>>(x, xb, 2097152);
  convert_kernel<<<dim3(384), 256, 0, stream>>>(Wqkv, wqkvb, 98304);
  // qkv = x @ Wqkv^T  -> bf16 [32768,1536]
  gemm_kernel<256, 256, 1536, false, false, false><<<dim3(256, 12), 256, 0, stream>>>(xb, wqkvb, nullptr, qkvb);
  // instance-norm k,v in place
  norm_kernel<<<dim3(32768), 256, 0, stream>>>(qkvb);
  // dots = khat^T vhat per (b,h)
  dots_kernel<<<dim3(32, 32), 256, 0, stream>>>(qkvb, dots);
  // fold (1/n) * dots @ Wout into per-b weight M2 [4,256,512]
  m2_kernel<<<dim3(4, 256), 512, 0, stream>>>(dots, Wout, m2);
  // out = q @ M2^T + bout  -> f32 [32768,256]
  gemm_kernel<512, 1536, 256, true, true, true><<<dim3(256, 2), 256, 0, stream>>>(qkvb, m2, bout, d_out);
}

// Round 2
// 205.640 us; speedup vs baseline: 2.0150x; 2.0150x over previous
//
#include <hip/hip_runtime.h>
#include <hip/hip_bf16.h>

// Problem constants: b=4, n=8192, dim=256, heads=8, dhead=64, inner=512
#define SEQ    8192
#define NROWS  32768      // b*n
#define F3     1536       // 3*inner
#define EPS    1e-5f

typedef __attribute__((ext_vector_type(4))) float f32x4;
typedef __attribute__((ext_vector_type(8))) short bf16x8;          // 8 bf16 (MFMA A/B frag)
typedef __attribute__((ext_vector_type(8))) unsigned short u16x8;  // 16B bf16 load

__device__ __forceinline__ unsigned short f2bu(float f) {
  __hip_bfloat16 h = __float2bfloat16(f);
  return __builtin_bit_cast(unsigned short, h);
}
__device__ __forceinline__ float b2f(unsigned short u) {
  return __bfloat162float(__builtin_bit_cast(__hip_bfloat16, u));
}

// ---------------------------------------------------------------- convert f32 -> bf16 (x4 vectorized)
__global__ __launch_bounds__(256) void convert_kernel(const float* __restrict__ in,
                                                      unsigned short* __restrict__ out, int n4) {
  int i = blockIdx.x * 256 + threadIdx.x;
  if (i >= n4) return;
  float4 v = reinterpret_cast<const float4*>(in)[i];
  ushort4 o;
  o.x = f2bu(v.x); o.y = f2bu(v.y); o.z = f2bu(v.z); o.w = f2bu(v.w);
  reinterpret_cast<ushort4*>(out)[i] = o;
}

// ---------------------------------------------------------------- bf16 MFMA GEMM: C[m,c] = sum_k A[m,k]*Bw[c,k]
// m97 structure: 128x128 tile, BK=64, 4 waves (2x2 of 64x64), global_load_lds width=16, 2-barrier loop.
template<int K, int LDA, int LDC, bool PERB, bool BIAS, bool OUTF32>
__global__ __launch_bounds__(256) void gemm_kernel(const unsigned short* __restrict__ A,
                                                   const unsigned short* __restrict__ Bw,
                                                   const float* __restrict__ bias,
                                                   void* __restrict__ Cout) {
  __shared__ unsigned short As[128 * 64];
  __shared__ unsigned short Bs[128 * 64];
  const int row0 = blockIdx.x * 128;
  const int col0 = blockIdx.y * 128;
  const unsigned short* Bp = Bw;
  if constexpr (PERB) Bp += (size_t)(row0 >> 13) * (size_t)(LDC * K);
  const int tid  = threadIdx.x;
  const int lane = tid & 63;
  const int wave = tid >> 6;
  const int wr = (wave >> 1) << 6;
  const int wc = (wave & 1) << 6;
  const int srow = tid >> 3;
  const int scol = (tid & 7) << 3;

  f32x4 acc[4][4] = {};

  for (int k0 = 0; k0 < K; k0 += 64) {
#pragma unroll
    for (int it = 0; it < 4; ++it) {
      const unsigned short* ga = A + (size_t)(row0 + it * 32 + srow) * LDA + (k0 + scol);
      __builtin_amdgcn_global_load_lds(
          (const __attribute__((address_space(1))) void*)ga,
          (__attribute__((address_space(3))) void*)((char*)As + (it * 4096 + wave * 1024)),
          16, 0, 0);
      const unsigned short* gb = Bp + (size_t)(col0 + it * 32 + srow) * K + (k0 + scol);
      __builtin_amdgcn_global_load_lds(
          (const __attribute__((address_space(1))) void*)gb,
          (__attribute__((address_space(3))) void*)((char*)Bs + (it * 4096 + wave * 1024)),
          16, 0, 0);
    }
    __syncthreads();
#pragma unroll
    for (int ks = 0; ks < 2; ++ks) {
      bf16x8 af[4], bfr[4];
#pragma unroll
      for (int mt = 0; mt < 4; ++mt)
        af[mt] = *reinterpret_cast<const bf16x8*>(
            &As[(wr + mt * 16 + (lane & 15)) * 64 + ks * 32 + (lane >> 4) * 8]);
#pragma unroll
      for (int nt = 0; nt < 4; ++nt)
        bfr[nt] = *reinterpret_cast<const bf16x8*>(
            &Bs[(wc + nt * 16 + (lane & 15)) * 64 + ks * 32 + (lane >> 4) * 8]);
#pragma unroll
      for (int mt = 0; mt < 4; ++mt)
#pragma unroll
        for (int nt = 0; nt < 4; ++nt)
          acc[mt][nt] = __builtin_amdgcn_mfma_f32_16x16x32_bf16(af[mt], bfr[nt], acc[mt][nt], 0, 0, 0);
    }
    __syncthreads();
  }
#pragma unroll
  for (int mt = 0; mt < 4; ++mt) {
#pragma unroll
    for (int nt = 0; nt < 4; ++nt) {
      const int col = col0 + wc + nt * 16 + (lane & 15);
      float bv = 0.0f;
      if constexpr (BIAS) bv = bias[col];
#pragma unroll
      for (int i = 0; i < 4; ++i) {
        const int row = row0 + wr + mt * 16 + ((lane >> 4) << 2) + i;
        float v = acc[mt][nt][i] + bv;
        if constexpr (OUTF32)
          reinterpret_cast<float*>(Cout)[(size_t)row * LDC + col] = v;
        else
          reinterpret_cast<unsigned short*>(Cout)[(size_t)row * LDC + col] = f2bu(v);
      }
    }
  }
}

// ---------------------------------------------------------------- fused instance-norm + partial k^T v
// grid (32 bh, 16 chunks), block 256. Each block: 512 rows, 16 stages of 32 rows.
// Stage: load raw k,v (bf16) -> 4-lane shfl norm (f32) -> LDS f32 -> register-tile outer product.
// Thread owns 4d x 4e of the 64x64 output; partial written to ws (no atomics).
// LDS: [2 buf][k:32x68 | pad4 | v:32x68] f32; stride 68 + v-offset 4 => <=2-way bank conflicts.
__global__ __launch_bounds__(256) void dots_kernel(const unsigned short* __restrict__ qkv,
                                                   float* __restrict__ partial) {
  const int bh = blockIdx.x;          // 0..31
  const int chunk = blockIdx.y;       // 0..15
  const int b = bh >> 3, h = bh & 7;
  const int t = threadIdx.x;
  __shared__ float lbuf[2][4360];     // 2 x 17440 B

  // staging role: r = row 0..31, j = 0..7 (j<4 -> k half, else v half), 16 elems each
  const int r  = t >> 3;
  const int j  = t & 7;
  const int kv = j >> 2;
  const int jj = j & 3;
  // compute role: 4d x 4e sub-tile
  const int dq = t & 15;
  const int eq = t >> 4;

  const size_t rowbase = (size_t)(b * SEQ + chunk * 512 + r) * F3 + 512 + kv * 512 + h * 64 + jj * 16;
  const int lds_off = kv * 2180 + r * 68 + jj * 16;

  float acc[4][4] = {};
  u16x8 raw0, raw1;
  raw0 = *reinterpret_cast<const u16x8*>(qkv + rowbase);           // rows 0..31 elems 0..7
  raw1 = *reinterpret_cast<const u16x8*>(qkv + rowbase + 8);       // elems 8..15

  // normalize + write helper expressed inline each use (kept in regs)
  int p = 0;
  {
    float x[16];
#pragma unroll
    for (int i = 0; i < 8; ++i) { x[i] = b2f(raw0[i]); x[8 + i] = b2f(raw1[i]); }
    float s = 0.f, s2 = 0.f;
#pragma unroll
    for (int i = 0; i < 16; ++i) { s += x[i]; s2 += x[i] * x[i]; }
    s += __shfl_xor(s, 1, 64);  s2 += __shfl_xor(s2, 1, 64);
    s += __shfl_xor(s, 2, 64);  s2 += __shfl_xor(s2, 2, 64);
    const float mean = s * (1.0f / 64.0f);
    float var = s2 * (1.0f / 64.0f) - mean * mean;
    var = var < 0.f ? 0.f : var;
    const float rs = rsqrtf(var + EPS);
    float* dst = &lbuf[0][lds_off];
#pragma unroll
    for (int i = 0; i < 4; ++i) {
      f32x4 o = { (x[4*i+0]-mean)*rs, (x[4*i+1]-mean)*rs, (x[4*i+2]-mean)*rs, (x[4*i+3]-mean)*rs };
      *reinterpret_cast<f32x4*>(dst + 4 * i) = o;
    }
  }

  for (int sIt = 0; sIt < 16; ++sIt) {
    const bool more = (sIt + 1) < 16;
    if (more) {
      const unsigned short* src = qkv + rowbase + (size_t)(sIt + 1) * 32 * F3;
      raw0 = *reinterpret_cast<const u16x8*>(src);
      raw1 = *reinterpret_cast<const u16x8*>(src + 8);
    }
    __syncthreads();   // lbuf[p] writes visible; previous compute on lbuf[p] complete
    {
      const float* lk = &lbuf[p][0];
      const float* lv = &lbuf[p][2180];
#pragma unroll 4
      for (int rr = 0; rr < 32; ++rr) {
        f32x4 kf = *reinterpret_cast<const f32x4*>(lk + rr * 68 + dq * 4);
        f32x4 vf = *reinterpret_cast<const f32x4*>(lv + rr * 68 + eq * 4);
#pragma unroll
        for (int i = 0; i < 4; ++i)
#pragma unroll
          for (int jx = 0; jx < 4; ++jx)
            acc[i][jx] = fmaf(kf[i], vf[jx], acc[i][jx]);
      }
    }
    if (more) {
      float x[16];
#pragma unroll
      for (int i = 0; i < 8; ++i) { x[i] = b2f(raw0[i]); x[8 + i] = b2f(raw1[i]); }
      float s = 0.f, s2 = 0.f;
#pragma unroll
      for (int i = 0; i < 16; ++i) { s += x[i]; s2 += x[i] * x[i]; }
      s += __shfl_xor(s, 1, 64);  s2 += __shfl_xor(s2, 1, 64);
      s += __shfl_xor(s, 2, 64);  s2 += __shfl_xor(s2, 2, 64);
      const float mean = s * (1.0f / 64.0f);
      float var = s2 * (1.0f / 64.0f) - mean * mean;
      var = var < 0.f ? 0.f : var;
      const float rs = rsqrtf(var + EPS);
      float* dst = &lbuf[p ^ 1][lds_off];
#pragma unroll
      for (int i = 0; i < 4; ++i) {
        f32x4 o = { (x[4*i+0]-mean)*rs, (x[4*i+1]-mean)*rs, (x[4*i+2]-mean)*rs, (x[4*i+3]-mean)*rs };
        *reinterpret_cast<f32x4*>(dst + 4 * i) = o;
      }
    }
    p ^= 1;
  }

  // write 64x64 partial: partial[(chunk*32+bh)*4096 + d*64 + e]
  float* pp = partial + ((size_t)(chunk * 32 + bh) << 12) + (size_t)(dq * 4) * 64 + eq * 4;
#pragma unroll
  for (int i = 0; i < 4; ++i) {
    f32x4 o = { acc[i][0], acc[i][1], acc[i][2], acc[i][3] };
    *reinterpret_cast<f32x4*>(pp + i * 64) = o;
  }
}

// ---------------------------------------------------------------- reduce 16 partials -> dots
__global__ __launch_bounds__(256) void reduce_kernel(const float* __restrict__ partial,
                                                     float* __restrict__ dots) {
  const int i = blockIdx.x * 256 + threadIdx.x;   // f32x4 index, 32768 total
  f32x4 s = {};
#pragma unroll
  for (int c = 0; c < 16; ++c)
    s += reinterpret_cast<const f32x4*>(partial)[(size_t)c * 32768 + i];
  reinterpret_cast<f32x4*>(dots)[i] = s;
}

// ---------------------------------------------------------------- M2[b,c,h*64+d] = (1/n) sum_e dots[b,h,d,e]*Wout[c,h*64+e]
__global__ __launch_bounds__(512) void m2_kernel(const float* __restrict__ dots,
                                                 const float* __restrict__ Wout,
                                                 unsigned short* __restrict__ M2) {
  const int b = blockIdx.x;
  const int c = blockIdx.y;
  const int t = threadIdx.x;
  __shared__ float wrow[512];
  wrow[t] = Wout[(size_t)c * 512 + t];
  __syncthreads();
  const int h = t >> 6, d = t & 63;
  const float* dp = dots + (size_t)(b * 8 + h) * 4096 + (size_t)d * 64;
  float s = 0.0f;
#pragma unroll 8
  for (int e = 0; e < 64; ++e) s += dp[e] * wrow[(h << 6) + e];
  M2[((size_t)b * 256 + c) * 512 + t] = f2bu(s * (1.0f / 8192.0f));
}

// ---------------------------------------------------------------- launch
extern "C" void kernel_launch(void* const* d_in, const int* in_sizes, int n_in,
                              void* d_out, int out_size, void* d_ws, size_t ws_size,
                              hipStream_t stream) {
  const float* x    = (const float*)d_in[0];   // [4,8192,256]
  const float* Wqkv = (const float*)d_in[1];   // [1536,256]
  const float* Wout = (const float*)d_in[2];   // [256,512]
  const float* bout = (const float*)d_in[3];   // [256]
  char* ws = (char*)d_ws;
  // workspace layout (16B aligned), total ~114.3 MB:
  //   [0, 16MB):      xb (bf16 x) -- DEAD after gemm1; partials (8MB) alias it afterwards
  unsigned short* xb    = (unsigned short*)(ws);                 // 16,777,216 B
  float*          part  = (float*)         (ws);                 //  8,388,608 B (aliases xb)
  unsigned short* wqkvb = (unsigned short*)(ws + 16777216);      //    786,432 B
  unsigned short* qkvb  = (unsigned short*)(ws + 17563648);      // 100,663,296 B
  float*          dots  = (float*)         (ws + 118226944);     //    524,288 B
  unsigned short* m2    = (unsigned short*)(ws + 118751232);     //  1,048,576 B

  convert_kernel<<<dim3(8192), 256, 0, stream>>>(x, xb, 2097152);
  convert_kernel<<<dim3(384), 256, 0, stream>>>(Wqkv, wqkvb, 98304);
  // qkv = x @ Wqkv^T  -> bf16 [32768,1536]
  gemm_kernel<256, 256, 1536, false, false, false><<<dim3(256, 12), 256, 0, stream>>>(xb, wqkvb, nullptr, qkvb);
  // fused instance-norm + k^T v partials (xb dead from here; same-stream ordering makes alias safe)
  dots_kernel<<<dim3(32, 16), 256, 0, stream>>>(qkvb, part);
  reduce_kernel<<<dim3(128), 256, 0, stream>>>(part, dots);
  // fold (1/n) * dots @ Wout into per-b weight M2 [4,256,512]
  m2_kernel<<<dim3(4, 256), 512, 0, stream>>>(dots, Wout, m2);
  // out = q @ M2^T + bout  -> f32 [32768,256]
  gemm_kernel<512, 1536, 256, true, true, true><<<dim3(256, 2), 256, 0, stream>>>(qkvb, m2, bout, d_out);
}